// Round 1
// baseline (99.848 us; speedup 1.0000x reference)
//
#include <hip/hip_runtime.h>

#define HH_DIM 2048
#define WW_DIM 2048
#define NF 64
#define MAX_DEPTH 12

// Kernel 1: build packed node + color tables in workspace.
//   node[f]  = float2{ ratio[f], int(left_child | right_child << 16) }
//   cpack[f] = float4{ r, g, b, 0 }
// First-max semantics (strict >) to match jnp.argmax.
__global__ void prep_kernel(const float* __restrict__ sel,     // [NF,2,NF]
                            const float* __restrict__ ratios,  // [NF]
                            const float* __restrict__ colors,  // [NF,3]
                            float2* __restrict__ node,         // [NF]
                            float4* __restrict__ cpack) {      // [NF]
    __shared__ int s_child[2 * NF];
    int t = threadIdx.x;
    if (t < 2 * NF) {
        const float* row = sel + t * NF;
        float best = row[0];
        int bi = 0;
        #pragma unroll
        for (int j = 1; j < NF; ++j) {
            float v = row[j];
            if (v > best) { best = v; bi = j; }
        }
        s_child[t] = bi;
    }
    __syncthreads();
    if (t < NF) {
        int packed = s_child[2 * t] | (s_child[2 * t + 1] << 16);
        node[t] = make_float2(ratios[t], __int_as_float(packed));
        cpack[t] = make_float4(colors[3 * t], colors[3 * t + 1], colors[3 * t + 2], 0.0f);
    }
}

// Kernel 2: per-pixel descent, 4 consecutive x-pixels per thread.
// Shared-path fast descent (all 4 pixels share y -> horizontal splits never
// diverge; vertical splits diverge only if the boundary lands strictly inside
// the 4-wide window, ~3% of threads). Rare forks replay from the saved state
// with a predicated 4-pixel lockstep loop.
__global__ __launch_bounds__(256)
void render_kernel(const float2* __restrict__ node,
                   const float4* __restrict__ cpack,
                   float* __restrict__ out) {                  // [3,H,W]
    __shared__ float2 s_node[NF];
    __shared__ float4 s_col[NF];

    int t = threadIdx.x;
    if (t < NF)            s_node[t] = node[t];
    else if (t < 2 * NF)   s_col[t - NF] = cpack[t - NF];
    __syncthreads();

    int gid = blockIdx.x * 256 + t;           // 1,048,576 threads
    int y  = gid >> 9;                         // 512 groups of 4 px per row
    int xb = (gid & 511) << 2;

    // Shared (group-uniform) descent. State in relative coords:
    //   rx = xb - x0, ry = y - y0  (pixel 0 of the group)
    int idx = 0, rx = xb, ry = y, w = WW_DIM, h = HH_DIM;
    int d = 0;
    bool div = false;
    for (; d < MAX_DEPTH; ++d) {
        if (w < 2 || h < 2) break;             // leaf (uniform for the group)
        float2 nd = s_node[idx];               // one ds_read_b64 per level
        int pk = __float_as_int(nd.y);
        int lc = pk & 0xffff, rcld = pk >> 16;
        bool vert = (idx & 1) != 0;
        int cs  = vert ? w  : h;
        int rc0 = vert ? rx : ry;
        int ls = (int)((float)cs * nd.x);      // trunc == floor (>=0)
        ls = ls < 1 ? 1 : ls;
        // group splits only on a vertical boundary strictly inside [rx, rx+3]
        if (vert & (rx < ls) & (ls <= rx + 3)) { div = true; break; }
        bool left = rc0 < ls;
        idx = left ? lc : rcld;
        int nr = left ? rc0 : rc0 - ls;
        int ns = left ? ls  : cs - ls;
        if (vert) { rx = nr; w = ns; } else { ry = nr; h = ns; }
    }

    int fidx0 = idx, fidx1 = idx, fidx2 = idx, fidx3 = idx;

    if (div) {
        // Fork: per-pixel lockstep descent from the saved pre-level-d state.
        int pidx[4], prx[4], pry[4], pw[4], ph[4];
        #pragma unroll
        for (int p = 0; p < 4; ++p) {
            pidx[p] = idx; prx[p] = rx + p; pry[p] = ry; pw[p] = w; ph[p] = h;
        }
        #pragma unroll 1
        for (int dd = d; dd < MAX_DEPTH; ++dd) {
            #pragma unroll
            for (int p = 0; p < 4; ++p) {
                float2 nd = s_node[pidx[p]];
                int pk = __float_as_int(nd.y);
                int lc = pk & 0xffff, rcld = pk >> 16;
                bool vert = (pidx[p] & 1) != 0;
                int cs  = vert ? pw[p]  : ph[p];
                int rc0 = vert ? prx[p] : pry[p];
                int ls = (int)((float)cs * nd.x);
                ls = ls < 1 ? 1 : ls;
                bool left = rc0 < ls;
                // leaf states are absorbing (sizes stay >=1, decisions stable);
                // only idx needs the activity guard.
                bool act = (pw[p] > 1) && (ph[p] > 1);
                int child = left ? lc : rcld;
                pidx[p] = act ? child : pidx[p];
                int nr = left ? rc0 : rc0 - ls;
                int ns = left ? ls  : cs - ls;
                if (vert) { prx[p] = nr; pw[p] = ns; }
                else      { pry[p] = nr; ph[p] = ns; }
            }
        }
        fidx0 = pidx[0]; fidx1 = pidx[1]; fidx2 = pidx[2]; fidx3 = pidx[3];
    }

    float4 k0 = s_col[fidx0];
    float4 k1 = s_col[fidx1];
    float4 k2 = s_col[fidx2];
    float4 k3 = s_col[fidx3];

    int base = y * WW_DIM + xb;
    const int plane = HH_DIM * WW_DIM;
    *(float4*)(out + base)             = make_float4(k0.x, k1.x, k2.x, k3.x);
    *(float4*)(out + plane + base)     = make_float4(k0.y, k1.y, k2.y, k3.y);
    *(float4*)(out + 2 * plane + base) = make_float4(k0.z, k1.z, k2.z, k3.z);
}

extern "C" void kernel_launch(void* const* d_in, const int* in_sizes, int n_in,
                              void* d_out, int out_size, void* d_ws, size_t ws_size,
                              hipStream_t stream) {
    const float* frame_colors    = (const float*)d_in[0];  // [64,3]
    const float* frame_selection = (const float*)d_in[1];  // [64,2,64]
    const float* split_ratios    = (const float*)d_in[2];  // [64]
    float* out = (float*)d_out;

    float2* node  = (float2*)d_ws;                 // 64 * 8 B
    float4* cpack = (float4*)((char*)d_ws + 1024); // 64 * 16 B (aligned)

    prep_kernel<<<1, 128, 0, stream>>>(frame_selection, split_ratios,
                                       frame_colors, node, cpack);
    render_kernel<<<4096, 256, 0, stream>>>(node, cpack, out);
}

// Round 2
// 95.289 us; speedup vs baseline: 1.0478x; 1.0478x over previous
//
#include <hip/hip_runtime.h>

#define HH_DIM 2048
#define WW_DIM 2048
#define NF 64
#define MAX_DEPTH 12

// Kernel 1: build packed node + color tables in workspace.
//   node[f]  = float2{ ratio[f], int(left_child | right_child << 16) }
//   cpack[f] = float4{ r, g, b, 0 }
// First-max semantics (strict >) to match jnp.argmax.
__global__ void prep_kernel(const float* __restrict__ sel,     // [NF,2,NF]
                            const float* __restrict__ ratios,  // [NF]
                            const float* __restrict__ colors,  // [NF,3]
                            float2* __restrict__ node,         // [NF]
                            float4* __restrict__ cpack) {      // [NF]
    __shared__ int s_child[2 * NF];
    int t = threadIdx.x;
    if (t < 2 * NF) {
        const float* row = sel + t * NF;
        float best = row[0];
        int bi = 0;
        #pragma unroll
        for (int j = 1; j < NF; ++j) {
            float v = row[j];
            if (v > best) { best = v; bi = j; }
        }
        s_child[t] = bi;
    }
    __syncthreads();
    if (t < NF) {
        int packed = s_child[2 * t] | (s_child[2 * t + 1] << 16);
        node[t] = make_float2(ratios[t], __int_as_float(packed));
        cpack[t] = make_float4(colors[3 * t], colors[3 * t + 1], colors[3 * t + 2], 0.0f);
    }
}

// Kernel 2: fully branchless lockstep descent. 4 consecutive x-pixels per
// thread, each descending MAX_DEPTH levels unconditionally via cndmask
// selects (zero divergent branches -> no wave-level slow-path
// amplification). Geometry kept in f32: all quantities are exact small
// integers, floorf/compare/sub are exact, so results are bit-identical to
// the int reference. Leaf states are absorbing: once min(w,h) < 2 the
// limiting dimension provably stays at 1 (vertical node with w==1 yields
// ls=1, left=true, w'=1; horizontal node never touches w), so guarding
// only idx is sufficient.
__global__ __launch_bounds__(256)
void render_kernel(const float2* __restrict__ node,
                   const float4* __restrict__ cpack,
                   float* __restrict__ out) {                  // [3,H,W]
    __shared__ float2 s_node[NF];
    __shared__ float4 s_col[NF];

    int t = threadIdx.x;
    if (t < NF)            s_node[t] = node[t];
    else if (t < 2 * NF)   s_col[t - NF] = cpack[t - NF];
    __syncthreads();

    int gid = blockIdx.x * 256 + t;           // 1,048,576 threads
    int y  = gid >> 9;                         // 512 groups of 4 px per row
    int xb = (gid & 511) << 2;

    int   idx[4];
    float rx[4], ry[4], w[4], h[4];
    #pragma unroll
    for (int p = 0; p < 4; ++p) {
        idx[p] = 0;
        rx[p] = (float)(xb + p);
        ry[p] = (float)y;
        w[p]  = (float)WW_DIM;
        h[p]  = (float)HH_DIM;
    }

    #pragma unroll
    for (int d = 0; d < MAX_DEPTH; ++d) {
        #pragma unroll
        for (int p = 0; p < 4; ++p) {
            float2 nd = s_node[idx[p]];        // one ds_read_b64
            int   pk  = __float_as_int(nd.y);
            bool  vert = (idx[p] & 1) != 0;
            float cs = vert ? w[p]  : h[p];
            float rc = vert ? rx[p] : ry[p];
            float ls = floorf(cs * nd.x);      // exact: ints < 2^24
            ls = fmaxf(ls, 1.0f);
            bool left = rc < ls;
            int  child = (pk >> (left ? 0 : 16)) & 63;
            bool act = fminf(w[p], h[p]) >= 2.0f;
            idx[p] = act ? child : idx[p];
            float rc2 = left ? rc : rc - ls;   // exact int sub
            float ns  = left ? ls : cs - ls;
            rx[p] = vert ? rc2  : rx[p];
            ry[p] = vert ? ry[p] : rc2;
            w[p]  = vert ? ns   : w[p];
            h[p]  = vert ? h[p] : ns;
        }
    }

    float4 k0 = s_col[idx[0]];
    float4 k1 = s_col[idx[1]];
    float4 k2 = s_col[idx[2]];
    float4 k3 = s_col[idx[3]];

    int base = y * WW_DIM + xb;
    const int plane = HH_DIM * WW_DIM;
    *(float4*)(out + base)             = make_float4(k0.x, k1.x, k2.x, k3.x);
    *(float4*)(out + plane + base)     = make_float4(k0.y, k1.y, k2.y, k3.y);
    *(float4*)(out + 2 * plane + base) = make_float4(k0.z, k1.z, k2.z, k3.z);
}

extern "C" void kernel_launch(void* const* d_in, const int* in_sizes, int n_in,
                              void* d_out, int out_size, void* d_ws, size_t ws_size,
                              hipStream_t stream) {
    const float* frame_colors    = (const float*)d_in[0];  // [64,3]
    const float* frame_selection = (const float*)d_in[1];  // [64,2,64]
    const float* split_ratios    = (const float*)d_in[2];  // [64]
    float* out = (float*)d_out;

    float2* node  = (float2*)d_ws;                 // 64 * 8 B
    float4* cpack = (float4*)((char*)d_ws + 1024); // 64 * 16 B (aligned)

    prep_kernel<<<1, 128, 0, stream>>>(frame_selection, split_ratios,
                                       frame_colors, node, cpack);
    render_kernel<<<4096, 256, 0, stream>>>(node, cpack, out);
}